// Round 1
// baseline (203.070 us; speedup 1.0000x reference)
//
#include <hip/hip_runtime.h>

// MarianAttention fused pipeline for MI355X (gfx950).
// B=2, T=2048, D=1024, H=16, DH=64. All matmuls via bf16 MFMA 16x16x32.
//
// Math notes (vs reference):
//  - scores are clamped to [1e-7, 1-1e-7] BEFORE softmax -> exp(S) in [1, e],
//    so no online-max is needed: accumulate l = sum(exp(S)), O = sum(exp(S) V),
//    final O/l. Post-softmax clamp and attn_out clamp are provable no-ops
//    (applied anyway where free, to absorb rounding).
//  - no NaNs can arise from finite inputs -> nan_to_num is a no-op.

typedef unsigned short u16;
using bf16x8 = __attribute__((ext_vector_type(8))) __bf16;
using f32x4  = __attribute__((ext_vector_type(4))) float;

#define GLD16(g, l) __builtin_amdgcn_global_load_lds(                      \
    (const __attribute__((address_space(1))) void*)(g),                    \
    (__attribute__((address_space(3))) void*)(l), 16, 0, 0)

__device__ __forceinline__ float clampf(float x) {
  return fminf(fmaxf(x, 1e-7f), 1.0f - 1e-7f);   // 1-1e-7 rounds to 0.99999988f, same as jnp f32
}

__device__ __forceinline__ u16 f2bf(float f) {   // RNE float->bf16 (no NaN inputs here)
  unsigned u = __float_as_uint(f);
  u += 0x7FFFu + ((u >> 16) & 1u);
  return (u16)(u >> 16);
}

// ---------------------------------------------------------------- converts
__global__ __launch_bounds__(256) void cvt_f32_to_bf16(
    const float4* __restrict__ src, ushort4* __restrict__ dst, int n4) {
  int i = blockIdx.x * 256 + threadIdx.x;
  if (i >= n4) return;
  float4 f = src[i];
  ushort4 o;
  o.x = f2bf(f.x); o.y = f2bf(f.y); o.z = f2bf(f.z); o.w = f2bf(f.w);
  dst[i] = o;
}

// ------------------------------------------------------------- GEMM core
// C[M,N] = A[M,1024] * B[N,1024]^T ; 128x128 tile, BK=64, 4 waves (2x2),
// each wave 64x64 = 4x4 frags of 16x16x32 MFMA. m97-style 2-barrier loop.
#define GEMM_CORE(Aptr, Bptr)                                              \
  for (int k0 = 0; k0 < 1024; k0 += 64) {                                  \
    _Pragma("unroll")                                                      \
    for (int i = 0; i < 4; ++i) {                                          \
      const int lin = i * 4096 + tid * 16;                                 \
      const int row = lin >> 7;                                            \
      const int inb = lin & 127;                                           \
      GLD16(Aptr + (size_t)(m0 + row) * 1024 + k0 + (inb >> 1),            \
            (char*)sA + i * 4096 + wave * 1024);                           \
      GLD16(Bptr + (size_t)(n0 + row) * 1024 + k0 + (inb >> 1),            \
            (char*)sB + i * 4096 + wave * 1024);                           \
    }                                                                      \
    __syncthreads();                                                       \
    _Pragma("unroll")                                                      \
    for (int kk = 0; kk < 2; ++kk) {                                       \
      const int ko = kk * 32 + lg * 8;                                     \
      bf16x8 af[4], bfr[4];                                                \
      _Pragma("unroll")                                                    \
      for (int mi = 0; mi < 4; ++mi)                                       \
        af[mi] = *(const bf16x8*)(sA + (wm * 64 + mi * 16 + lr) * 64 + ko);\
      _Pragma("unroll")                                                    \
      for (int ni = 0; ni < 4; ++ni)                                       \
        bfr[ni] = *(const bf16x8*)(sB + (wn * 64 + ni * 16 + lr) * 64 + ko);\
      _Pragma("unroll")                                                    \
      for (int mi = 0; mi < 4; ++mi)                                       \
        _Pragma("unroll")                                                  \
        for (int ni = 0; ni < 4; ++ni)                                     \
          acc[mi][ni] = __builtin_amdgcn_mfma_f32_16x16x32_bf16(           \
              af[mi], bfr[ni], acc[mi][ni], 0, 0, 0);                      \
    }                                                                      \
    __syncthreads();                                                       \
  }

// QKV projection: z=0 -> Q (scale 0.125), z=1 -> K, z=2 -> V (transposed store).
// Q,K out: token-major [4096][1024] bf16. V out: Vt [B*H=32][DH=64][T=2048] bf16.
__global__ __launch_bounds__(256) void gemm_qkv(
    const u16* __restrict__ Xb,
    const u16* __restrict__ Wqb, const u16* __restrict__ Wkb, const u16* __restrict__ Wvb,
    const float* __restrict__ bq, const float* __restrict__ bk, const float* __restrict__ bv,
    u16* __restrict__ Qo, u16* __restrict__ Ko, u16* __restrict__ Vt)
{
  __shared__ u16 sA[128 * 64];
  __shared__ u16 sB[128 * 64];
  const int tid = threadIdx.x, lane = tid & 63, wave = tid >> 6;
  const int lr = lane & 15, lg = lane >> 4;
  const int wm = wave >> 1, wn = wave & 1;
  const int n0 = blockIdx.x * 128, m0 = blockIdx.y * 128;
  const int p = blockIdx.z;
  const u16*   Wb   = (p == 0) ? Wqb : (p == 1) ? Wkb : Wvb;
  const float* bias = (p == 0) ? bq  : (p == 1) ? bk  : bv;
  const float  scale = (p == 0) ? 0.125f : 1.0f;

  f32x4 acc[4][4] = {};
  GEMM_CORE(Xb, Wb)

  if (p == 2) {
    // V: write transposed Vt[(b*16+h)*64 + dh][t]; j=0..3 are consecutive t -> pack 8B
    #pragma unroll
    for (int ni = 0; ni < 4; ++ni) {
      const int n = n0 + wn * 64 + ni * 16 + lr;       // feature
      const float bb = bias[n];
      #pragma unroll
      for (int mi = 0; mi < 4; ++mi) {
        const int m = m0 + wm * 64 + mi * 16 + lg * 4; // token (j=0)
        ushort4 pk;
        pk.x = f2bf(clampf(acc[mi][ni][0] + bb));
        pk.y = f2bf(clampf(acc[mi][ni][1] + bb));
        pk.z = f2bf(clampf(acc[mi][ni][2] + bb));
        pk.w = f2bf(clampf(acc[mi][ni][3] + bb));
        *(ushort4*)(Vt + ((size_t)((m >> 11) * 16 + (n >> 6)) * 64 + (n & 63)) * 2048
                       + (m & 2047)) = pk;
      }
    }
  } else {
    u16* O = (p == 0) ? Qo : Ko;
    #pragma unroll
    for (int ni = 0; ni < 4; ++ni) {
      const int n = n0 + wn * 64 + ni * 16 + lr;
      const float bb = bias[n];
      #pragma unroll
      for (int mi = 0; mi < 4; ++mi) {
        #pragma unroll
        for (int j = 0; j < 4; ++j) {
          const int m = m0 + wm * 64 + mi * 16 + lg * 4 + j;
          O[(size_t)m * 1024 + n] = f2bf(clampf((acc[mi][ni][j] + bb) * scale));
        }
      }
    }
  }
}

// Output projection: out = clamp(AO * Wo^T + bo), fp32 store.
__global__ __launch_bounds__(256) void gemm_out(
    const u16* __restrict__ AOb, const u16* __restrict__ Wob,
    const float* __restrict__ bo, float* __restrict__ out)
{
  __shared__ u16 sA[128 * 64];
  __shared__ u16 sB[128 * 64];
  const int tid = threadIdx.x, lane = tid & 63, wave = tid >> 6;
  const int lr = lane & 15, lg = lane >> 4;
  const int wm = wave >> 1, wn = wave & 1;
  const int n0 = blockIdx.x * 128, m0 = blockIdx.y * 128;

  f32x4 acc[4][4] = {};
  GEMM_CORE(AOb, Wob)

  #pragma unroll
  for (int ni = 0; ni < 4; ++ni) {
    const int n = n0 + wn * 64 + ni * 16 + lr;
    const float bb = bo[n];
    #pragma unroll
    for (int mi = 0; mi < 4; ++mi) {
      #pragma unroll
      for (int j = 0; j < 4; ++j) {
        const int m = m0 + wm * 64 + mi * 16 + lg * 4 + j;
        out[(size_t)m * 1024 + n] = clampf(acc[mi][ni][j] + bb);
      }
    }
  }
}

// ------------------------------------------------------------- attention
// One block per (q-tile of 128 rows, b*h). 4 waves; wave w owns q-rows
// [w*32, w*32+32). Streaming over 16 KV tiles of 128. No online max needed
// (scores clamped to <=1). P tile round-trips through LDS (per-wave rows only).
__global__ __launch_bounds__(256) void attn_fused(
    const u16* __restrict__ Qg, const u16* __restrict__ Kg,
    const u16* __restrict__ Vt, u16* __restrict__ AO)
{
  __shared__ u16 sQ[128 * 64];
  __shared__ u16 sK[128 * 64];
  __shared__ u16 sV[64 * 128];    // V^T tile: [dh][s]
  __shared__ u16 sP[128 * 128];
  const int tid = threadIdx.x, lane = tid & 63, wave = tid >> 6;
  const int lr = lane & 15, lg = lane >> 4;
  const int qt = blockIdx.x, bh = blockIdx.y;
  const int b = bh >> 4, h = bh & 15;

  f32x4 oacc[2][4] = {};
  float lsum[2][4] = {};

  // stage Q tile [128 q-rows][64 dh]
  #pragma unroll
  for (int i = 0; i < 4; ++i) {
    const int lin = i * 4096 + tid * 16;
    const int row = lin >> 7, inb = lin & 127;
    GLD16(Qg + (size_t)(b * 2048 + qt * 128 + row) * 1024 + h * 64 + (inb >> 1),
          (char*)sQ + i * 4096 + wave * 1024);
  }

  for (int s0 = 0; s0 < 2048; s0 += 128) {
    // stage K tile [128 s][64 dh] and V^T tile [64 dh][128 s]
    #pragma unroll
    for (int i = 0; i < 4; ++i) {
      const int lin = i * 4096 + tid * 16;
      const int row = lin >> 7, inb = lin & 127;
      GLD16(Kg + (size_t)(b * 2048 + s0 + row) * 1024 + h * 64 + (inb >> 1),
            (char*)sK + i * 4096 + wave * 1024);
      const int rowv = lin >> 8, inbv = lin & 255;
      GLD16(Vt + ((size_t)bh * 64 + rowv) * 2048 + s0 + (inbv >> 1),
            (char*)sV + i * 4096 + wave * 1024);
    }
    __syncthreads();

    // S = Q K^T for this wave's 32 rows x 128 cols
    f32x4 sacc[2][8] = {};
    #pragma unroll
    for (int kk = 0; kk < 2; ++kk) {
      const int ko = kk * 32 + lg * 8;
      bf16x8 aq[2], bk8[8];
      #pragma unroll
      for (int mi = 0; mi < 2; ++mi)
        aq[mi] = *(const bf16x8*)(sQ + (wave * 32 + mi * 16 + lr) * 64 + ko);
      #pragma unroll
      for (int ni = 0; ni < 8; ++ni)
        bk8[ni] = *(const bf16x8*)(sK + (ni * 16 + lr) * 64 + ko);
      #pragma unroll
      for (int mi = 0; mi < 2; ++mi)
        #pragma unroll
        for (int ni = 0; ni < 8; ++ni)
          sacc[mi][ni] = __builtin_amdgcn_mfma_f32_16x16x32_bf16(
              aq[mi], bk8[ni], sacc[mi][ni], 0, 0, 0);
    }

    // clamp -> exp -> row-sum, P to LDS as bf16 (only this wave's rows)
    #pragma unroll
    for (int mi = 0; mi < 2; ++mi)
      #pragma unroll
      for (int ni = 0; ni < 8; ++ni)
        #pragma unroll
        for (int j = 0; j < 4; ++j) {
          float e = __expf(clampf(sacc[mi][ni][j]));
          lsum[mi][j] += e;
          sP[(wave * 32 + mi * 16 + lg * 4 + j) * 128 + ni * 16 + lr] = f2bf(e);
        }
    // same-wave LDS write->read: in-order per wave + compiler lgkmcnt; no barrier needed.

    // O += P V   (k = s, 128 wide; B-operand = sV[d][s] is k-contiguous)
    #pragma unroll
    for (int kk = 0; kk < 4; ++kk) {
      const int ko = kk * 32 + lg * 8;
      bf16x8 ap[2], bv8[4];
      #pragma unroll
      for (int mi = 0; mi < 2; ++mi)
        ap[mi] = *(const bf16x8*)(sP + (wave * 32 + mi * 16 + lr) * 128 + ko);
      #pragma unroll
      for (int ni = 0; ni < 4; ++ni)
        bv8[ni] = *(const bf16x8*)(sV + (ni * 16 + lr) * 128 + ko);
      #pragma unroll
      for (int mi = 0; mi < 2; ++mi)
        #pragma unroll
        for (int ni = 0; ni < 4; ++ni)
          oacc[mi][ni] = __builtin_amdgcn_mfma_f32_16x16x32_bf16(
              ap[mi], bv8[ni], oacc[mi][ni], 0, 0, 0);
    }
    __syncthreads();   // all waves done reading sK/sV before next stage
  }

  // finalize: row sums across the 16 lanes of each col-group, divide, store
  #pragma unroll
  for (int mi = 0; mi < 2; ++mi) {
    #pragma unroll
    for (int j = 0; j < 4; ++j) {
      float l = lsum[mi][j];
      l += __shfl_xor(l, 1);
      l += __shfl_xor(l, 2);
      l += __shfl_xor(l, 4);
      l += __shfl_xor(l, 8);
      const float inv = 1.0f / l;
      const int m = qt * 128 + wave * 32 + mi * 16 + lg * 4 + j;
      #pragma unroll
      for (int ni = 0; ni < 4; ++ni) {
        float v = oacc[mi][ni][j] * inv;
        AO[(size_t)(b * 2048 + m) * 1024 + h * 64 + ni * 16 + lr] = f2bf(clampf(v));
      }
    }
  }
}

// ---------------------------------------------------------------- launch
extern "C" void kernel_launch(void* const* d_in, const int* in_sizes, int n_in,
                              void* d_out, int out_size, void* d_ws, size_t ws_size,
                              hipStream_t stream) {
  const float* X  = (const float*)d_in[0];
  const float* Wq = (const float*)d_in[1];
  const float* bq = (const float*)d_in[2];
  const float* Wk = (const float*)d_in[3];
  const float* bk = (const float*)d_in[4];
  const float* Wv = (const float*)d_in[5];
  const float* bv = (const float*)d_in[6];
  const float* Wo = (const float*)d_in[7];
  const float* bo = (const float*)d_in[8];
  float* out = (float*)d_out;

  if (ws_size < (size_t)48 * 1024 * 1024) return;  // fail loudly (output stays poisoned)

  u16* ws  = (u16*)d_ws;
  u16* Xb  = ws;                         // [4096][1024]  8 MB
  u16* Wqb = ws + (size_t)4  * 1048576;  // [1024][1024]  2 MB
  u16* Wkb = ws + (size_t)5  * 1048576;
  u16* Wvb = ws + (size_t)6  * 1048576;
  u16* Wob = ws + (size_t)7  * 1048576;
  u16* Qb  = ws + (size_t)8  * 1048576;  // [4096][1024]  8 MB
  u16* Kb  = ws + (size_t)12 * 1048576;
  u16* Vtb = ws + (size_t)16 * 1048576;  // [32][64][2048] 8 MB
  u16* AOb = ws + (size_t)20 * 1048576;  // [4096][1024]  8 MB

  cvt_f32_to_bf16<<<4096, 256, 0, stream>>>((const float4*)X,  (ushort4*)Xb,  1048576);
  cvt_f32_to_bf16<<<1024, 256, 0, stream>>>((const float4*)Wq, (ushort4*)Wqb, 262144);
  cvt_f32_to_bf16<<<1024, 256, 0, stream>>>((const float4*)Wk, (ushort4*)Wkb, 262144);
  cvt_f32_to_bf16<<<1024, 256, 0, stream>>>((const float4*)Wv, (ushort4*)Wvb, 262144);
  cvt_f32_to_bf16<<<1024, 256, 0, stream>>>((const float4*)Wo, (ushort4*)Wob, 262144);

  gemm_qkv<<<dim3(8, 32, 3), 256, 0, stream>>>(Xb, Wqb, Wkb, Wvb, bq, bk, bv, Qb, Kb, Vtb);
  attn_fused<<<dim3(16, 32), 256, 0, stream>>>(Qb, Kb, Vtb, AOb);
  gemm_out<<<dim3(8, 32), 256, 0, stream>>>(AOb, Wob, bo, out);
}

// Round 2
// 190.102 us; speedup vs baseline: 1.0682x; 1.0682x over previous
//
#include <hip/hip_runtime.h>

// MarianAttention fused pipeline for MI355X (gfx950).
// B=2, T=2048, D=1024, H=16, DH=64. All matmuls via bf16 MFMA 16x16x32.
//
// Math notes (vs reference):
//  - scores are clamped to [1e-7, 1-1e-7] BEFORE softmax -> exp(S) in [1, e],
//    so no online-max is needed: accumulate l = sum(exp(S)), O = sum(exp(S) V),
//    final O/l. Post-softmax clamp and attn_out clamp are provable no-ops
//    (applied anyway where free, to absorb rounding).
//  - no NaNs can arise from finite inputs -> nan_to_num is a no-op.
//
// R1: XOR-swizzled LDS in attn (T2, both-sides: pre-swizzled GLD16 source +
//     swizzled ds_read; sP swizzled on write and read), Q fragments hoisted
//     to registers, round-half-up bf16 convert, setprio around MFMA.

typedef unsigned short u16;
using bf16x8 = __attribute__((ext_vector_type(8))) __bf16;
using f32x4  = __attribute__((ext_vector_type(4))) float;

#define GLD16(g, l) __builtin_amdgcn_global_load_lds(                      \
    (const __attribute__((address_space(1))) void*)(g),                    \
    (__attribute__((address_space(3))) void*)(l), 16, 0, 0)

__device__ __forceinline__ float clampf(float x) {
  return fminf(fmaxf(x, 1e-7f), 1.0f - 1e-7f);
}

__device__ __forceinline__ u16 f2bf(float f) {   // round-half-up f32->bf16 (no NaNs here)
  return (u16)((__float_as_uint(f) + 0x8000u) >> 16);
}

// ---------------------------------------------------------------- converts
__global__ __launch_bounds__(256) void cvt_f32_to_bf16(
    const float4* __restrict__ src, ushort4* __restrict__ dst, int n4) {
  int i = blockIdx.x * 256 + threadIdx.x;
  if (i >= n4) return;
  float4 f = src[i];
  ushort4 o;
  o.x = f2bf(f.x); o.y = f2bf(f.y); o.z = f2bf(f.z); o.w = f2bf(f.w);
  dst[i] = o;
}

// ------------------------------------------------------------- GEMM core
// C[M,N] = A[M,1024] * B[N,1024]^T ; 128x128 tile, BK=64, 4 waves (2x2),
// each wave 64x64 = 4x4 frags of 16x16x32 MFMA. m97-style 2-barrier loop.
#define GEMM_CORE(Aptr, Bptr)                                              \
  for (int k0 = 0; k0 < 1024; k0 += 64) {                                  \
    _Pragma("unroll")                                                      \
    for (int i = 0; i < 4; ++i) {                                          \
      const int lin = i * 4096 + tid * 16;                                 \
      const int row = lin >> 7;                                            \
      const int inb = lin & 127;                                           \
      GLD16(Aptr + (size_t)(m0 + row) * 1024 + k0 + (inb >> 1),            \
            (char*)sA + i * 4096 + wave * 1024);                           \
      GLD16(Bptr + (size_t)(n0 + row) * 1024 + k0 + (inb >> 1),            \
            (char*)sB + i * 4096 + wave * 1024);                           \
    }                                                                      \
    __syncthreads();                                                       \
    _Pragma("unroll")                                                      \
    for (int kk = 0; kk < 2; ++kk) {                                       \
      const int ko = kk * 32 + lg * 8;                                     \
      bf16x8 af[4], bfr[4];                                                \
      _Pragma("unroll")                                                    \
      for (int mi = 0; mi < 4; ++mi)                                       \
        af[mi] = *(const bf16x8*)(sA + (wm * 64 + mi * 16 + lr) * 64 + ko);\
      _Pragma("unroll")                                                    \
      for (int ni = 0; ni < 4; ++ni)                                       \
        bfr[ni] = *(const bf16x8*)(sB + (wn * 64 + ni * 16 + lr) * 64 + ko);\
      _Pragma("unroll")                                                    \
      for (int mi = 0; mi < 4; ++mi)                                       \
        _Pragma("unroll")                                                  \
        for (int ni = 0; ni < 4; ++ni)                                     \
          acc[mi][ni] = __builtin_amdgcn_mfma_f32_16x16x32_bf16(           \
              af[mi], bfr[ni], acc[mi][ni], 0, 0, 0);                      \
    }                                                                      \
    __syncthreads();                                                       \
  }

// QKV projection: z=0 -> Q (scale 0.125), z=1 -> K, z=2 -> V (transposed store).
// Q,K out: token-major [4096][1024] bf16. V out: Vt [B*H=32][DH=64][T=2048] bf16.
__global__ __launch_bounds__(256) void gemm_qkv(
    const u16* __restrict__ Xb,
    const u16* __restrict__ Wqb, const u16* __restrict__ Wkb, const u16* __restrict__ Wvb,
    const float* __restrict__ bq, const float* __restrict__ bk, const float* __restrict__ bv,
    u16* __restrict__ Qo, u16* __restrict__ Ko, u16* __restrict__ Vt)
{
  __shared__ u16 sA[128 * 64];
  __shared__ u16 sB[128 * 64];
  const int tid = threadIdx.x, lane = tid & 63, wave = tid >> 6;
  const int lr = lane & 15, lg = lane >> 4;
  const int wm = wave >> 1, wn = wave & 1;
  const int n0 = blockIdx.x * 128, m0 = blockIdx.y * 128;
  const int p = blockIdx.z;
  const u16*   Wb   = (p == 0) ? Wqb : (p == 1) ? Wkb : Wvb;
  const float* bias = (p == 0) ? bq  : (p == 1) ? bk  : bv;
  const float  scale = (p == 0) ? 0.125f : 1.0f;

  f32x4 acc[4][4] = {};
  GEMM_CORE(Xb, Wb)

  if (p == 2) {
    // V: write transposed Vt[(b*16+h)*64 + dh][t]; j=0..3 are consecutive t -> pack 8B
    #pragma unroll
    for (int ni = 0; ni < 4; ++ni) {
      const int n = n0 + wn * 64 + ni * 16 + lr;       // feature
      const float bb = bias[n];
      #pragma unroll
      for (int mi = 0; mi < 4; ++mi) {
        const int m = m0 + wm * 64 + mi * 16 + lg * 4; // token (j=0)
        ushort4 pk;
        pk.x = f2bf(clampf(acc[mi][ni][0] + bb));
        pk.y = f2bf(clampf(acc[mi][ni][1] + bb));
        pk.z = f2bf(clampf(acc[mi][ni][2] + bb));
        pk.w = f2bf(clampf(acc[mi][ni][3] + bb));
        *(ushort4*)(Vt + ((size_t)((m >> 11) * 16 + (n >> 6)) * 64 + (n & 63)) * 2048
                       + (m & 2047)) = pk;
      }
    }
  } else {
    u16* O = (p == 0) ? Qo : Ko;
    #pragma unroll
    for (int ni = 0; ni < 4; ++ni) {
      const int n = n0 + wn * 64 + ni * 16 + lr;
      const float bb = bias[n];
      #pragma unroll
      for (int mi = 0; mi < 4; ++mi) {
        #pragma unroll
        for (int j = 0; j < 4; ++j) {
          const int m = m0 + wm * 64 + mi * 16 + lg * 4 + j;
          O[(size_t)m * 1024 + n] = f2bf(clampf((acc[mi][ni][j] + bb) * scale));
        }
      }
    }
  }
}

// Output projection: out = clamp(AO * Wo^T + bo), fp32 store.
__global__ __launch_bounds__(256) void gemm_out(
    const u16* __restrict__ AOb, const u16* __restrict__ Wob,
    const float* __restrict__ bo, float* __restrict__ out)
{
  __shared__ u16 sA[128 * 64];
  __shared__ u16 sB[128 * 64];
  const int tid = threadIdx.x, lane = tid & 63, wave = tid >> 6;
  const int lr = lane & 15, lg = lane >> 4;
  const int wm = wave >> 1, wn = wave & 1;
  const int n0 = blockIdx.x * 128, m0 = blockIdx.y * 128;

  f32x4 acc[4][4] = {};
  GEMM_CORE(AOb, Wob)

  #pragma unroll
  for (int ni = 0; ni < 4; ++ni) {
    const int n = n0 + wn * 64 + ni * 16 + lr;
    const float bb = bo[n];
    #pragma unroll
    for (int mi = 0; mi < 4; ++mi) {
      #pragma unroll
      for (int j = 0; j < 4; ++j) {
        const int m = m0 + wm * 64 + mi * 16 + lg * 4 + j;
        out[(size_t)m * 1024 + n] = clampf(acc[mi][ni][j] + bb);
      }
    }
  }
}

// ------------------------------------------------------------- attention
// One block per (q-tile of 128 rows, b*h). 4 waves; wave w owns q-rows
// [w*32, w*32+32). Streaming over 16 KV tiles of 128. No online max needed.
// All LDS tiles XOR-swizzled (T2): data col c of row r lives at
// u16 index r*stride + (c ^ sw(r)); GLD16 tiles get the inverse applied to
// the GLOBAL source column (LDS dest stays linear), sP gets it on the write.
__global__ __launch_bounds__(256) void attn_fused(
    const u16* __restrict__ Qg, const u16* __restrict__ Kg,
    const u16* __restrict__ Vt, u16* __restrict__ AO)
{
  __shared__ u16 sQ[128 * 64];    // [qrow][dh]   sw(r) = (r&7)<<3
  __shared__ u16 sK[128 * 64];    // [s][dh]      sw(r) = (r&7)<<3
  __shared__ u16 sV[64 * 128];    // [dh][s]      sw(r) = (r&15)<<3
  __shared__ u16 sP[128 * 128];   // [qrow][s]    sw(r) = (r&15)<<3
  const int tid = threadIdx.x, lane = tid & 63, wave = tid >> 6;
  const int lr = lane & 15, lg = lane >> 4;
  const int qt = blockIdx.x, bh = blockIdx.y;
  const int b = bh >> 4, h = bh & 15;

  f32x4 oacc[2][4] = {};
  float lsum[2][4] = {};

  // stage Q tile [128 q-rows][64 dh], source pre-swizzled
  #pragma unroll
  for (int i = 0; i < 4; ++i) {
    const int lin = i * 4096 + tid * 16;
    const int row = lin >> 7;
    const int col = ((lin & 127) >> 1) ^ ((row & 7) << 3);
    GLD16(Qg + (size_t)(b * 2048 + qt * 128 + row) * 1024 + h * 64 + col,
          (char*)sQ + i * 4096 + wave * 1024);
  }
  __syncthreads();

  // hoist this wave's Q fragments into registers (read once, swizzled)
  bf16x8 aq[2][2];
  #pragma unroll
  for (int kk = 0; kk < 2; ++kk)
    #pragma unroll
    for (int mi = 0; mi < 2; ++mi) {
      const int row = wave * 32 + mi * 16 + lr;
      aq[kk][mi] = *(const bf16x8*)(sQ + row * 64 + ((kk * 32 + lg * 8) ^ ((row & 7) << 3)));
    }

  for (int s0 = 0; s0 < 2048; s0 += 128) {
    // stage K tile [128 s][64 dh] and V^T tile [64 dh][128 s], sources pre-swizzled
    #pragma unroll
    for (int i = 0; i < 4; ++i) {
      const int lin = i * 4096 + tid * 16;
      const int row  = lin >> 7;
      const int colk = ((lin & 127) >> 1) ^ ((row & 7) << 3);
      GLD16(Kg + (size_t)(b * 2048 + s0 + row) * 1024 + h * 64 + colk,
            (char*)sK + i * 4096 + wave * 1024);
      const int rowv = lin >> 8;
      const int colv = ((lin & 255) >> 1) ^ ((rowv & 15) << 3);
      GLD16(Vt + ((size_t)bh * 64 + rowv) * 2048 + s0 + colv,
            (char*)sV + i * 4096 + wave * 1024);
    }
    __syncthreads();

    // S = Q K^T for this wave's 32 rows x 128 cols
    f32x4 sacc[2][8] = {};
    __builtin_amdgcn_s_setprio(1);
    #pragma unroll
    for (int kk = 0; kk < 2; ++kk) {
      const int ko = kk * 32 + lg * 8;
      bf16x8 bk8[8];
      #pragma unroll
      for (int ni = 0; ni < 8; ++ni) {
        const int row = ni * 16 + lr;
        bk8[ni] = *(const bf16x8*)(sK + row * 64 + (ko ^ ((row & 7) << 3)));
      }
      #pragma unroll
      for (int mi = 0; mi < 2; ++mi)
        #pragma unroll
        for (int ni = 0; ni < 8; ++ni)
          sacc[mi][ni] = __builtin_amdgcn_mfma_f32_16x16x32_bf16(
              aq[kk][mi], bk8[ni], sacc[mi][ni], 0, 0, 0);
    }
    __builtin_amdgcn_s_setprio(0);

    // clamp -> exp -> row-sum, P to LDS as bf16 (this wave's rows only, swizzled)
    #pragma unroll
    for (int mi = 0; mi < 2; ++mi)
      #pragma unroll
      for (int ni = 0; ni < 8; ++ni)
        #pragma unroll
        for (int j = 0; j < 4; ++j) {
          float e = __expf(clampf(sacc[mi][ni][j]));
          lsum[mi][j] += e;
          const int prow = wave * 32 + mi * 16 + lg * 4 + j;
          sP[prow * 128 + ((ni * 16 + lr) ^ ((prow & 15) << 3))] = f2bf(e);
        }
    // same-wave LDS write->read below: in-order per wave, no barrier needed.

    // O += P V   (k = s, 128 wide; B-operand = sV[d][s] is k-contiguous)
    __builtin_amdgcn_s_setprio(1);
    #pragma unroll
    for (int kk = 0; kk < 4; ++kk) {
      const int ko = kk * 32 + lg * 8;
      bf16x8 ap[2], bv8[4];
      #pragma unroll
      for (int mi = 0; mi < 2; ++mi) {
        const int prow = wave * 32 + mi * 16 + lr;
        ap[mi] = *(const bf16x8*)(sP + prow * 128 + (ko ^ ((prow & 15) << 3)));
      }
      #pragma unroll
      for (int ni = 0; ni < 4; ++ni) {
        const int vrow = ni * 16 + lr;
        bv8[ni] = *(const bf16x8*)(sV + vrow * 128 + (ko ^ ((vrow & 15) << 3)));
      }
      #pragma unroll
      for (int mi = 0; mi < 2; ++mi)
        #pragma unroll
        for (int ni = 0; ni < 4; ++ni)
          oacc[mi][ni] = __builtin_amdgcn_mfma_f32_16x16x32_bf16(
              ap[mi], bv8[ni], oacc[mi][ni], 0, 0, 0);
    }
    __builtin_amdgcn_s_setprio(0);
    __syncthreads();   // all waves done reading sK/sV before next stage
  }

  // finalize: row sums across the 16 lanes of each col-group, divide, store
  #pragma unroll
  for (int mi = 0; mi < 2; ++mi) {
    #pragma unroll
    for (int j = 0; j < 4; ++j) {
      float l = lsum[mi][j];
      l += __shfl_xor(l, 1);
      l += __shfl_xor(l, 2);
      l += __shfl_xor(l, 4);
      l += __shfl_xor(l, 8);
      const float inv = 1.0f / l;
      const int m = qt * 128 + wave * 32 + mi * 16 + lg * 4 + j;
      #pragma unroll
      for (int ni = 0; ni < 4; ++ni) {
        float v = oacc[mi][ni][j] * inv;
        AO[(size_t)(b * 2048 + m) * 1024 + h * 64 + ni * 16 + lr] = f2bf(clampf(v));
      }
    }
  }
}

// ---------------------------------------------------------------- launch
extern "C" void kernel_launch(void* const* d_in, const int* in_sizes, int n_in,
                              void* d_out, int out_size, void* d_ws, size_t ws_size,
                              hipStream_t stream) {
  const float* X  = (const float*)d_in[0];
  const float* Wq = (const float*)d_in[1];
  const float* bq = (const float*)d_in[2];
  const float* Wk = (const float*)d_in[3];
  const float* bk = (const float*)d_in[4];
  const float* Wv = (const float*)d_in[5];
  const float* bv = (const float*)d_in[6];
  const float* Wo = (const float*)d_in[7];
  const float* bo = (const float*)d_in[8];
  float* out = (float*)d_out;

  if (ws_size < (size_t)48 * 1024 * 1024) return;  // fail loudly (output stays poisoned)

  u16* ws  = (u16*)d_ws;
  u16* Xb  = ws;                         // [4096][1024]  8 MB
  u16* Wqb = ws + (size_t)4  * 1048576;  // [1024][1024]  2 MB
  u16* Wkb = ws + (size_t)5  * 1048576;
  u16* Wvb = ws + (size_t)6  * 1048576;
  u16* Wob = ws + (size_t)7  * 1048576;
  u16* Qb  = ws + (size_t)8  * 1048576;  // [4096][1024]  8 MB
  u16* Kb  = ws + (size_t)12 * 1048576;
  u16* Vtb = ws + (size_t)16 * 1048576;  // [32][64][2048] 8 MB
  u16* AOb = ws + (size_t)20 * 1048576;  // [4096][1024]  8 MB

  cvt_f32_to_bf16<<<4096, 256, 0, stream>>>((const float4*)X,  (ushort4*)Xb,  1048576);
  cvt_f32_to_bf16<<<1024, 256, 0, stream>>>((const float4*)Wq, (ushort4*)Wqb, 262144);
  cvt_f32_to_bf16<<<1024, 256, 0, stream>>>((const float4*)Wk, (ushort4*)Wkb, 262144);
  cvt_f32_to_bf16<<<1024, 256, 0, stream>>>((const float4*)Wv, (ushort4*)Wvb, 262144);
  cvt_f32_to_bf16<<<1024, 256, 0, stream>>>((const float4*)Wo, (ushort4*)Wob, 262144);

  gemm_qkv<<<dim3(8, 32, 3), 256, 0, stream>>>(Xb, Wqb, Wkb, Wvb, bq, bk, bv, Qb, Kb, Vtb);
  attn_fused<<<dim3(16, 32), 256, 0, stream>>>(Qb, Kb, Vtb, AOb);
  gemm_out<<<dim3(8, 32), 256, 0, stream>>>(AOb, Wob, bo, out);
}

// Round 4
// 165.506 us; speedup vs baseline: 1.2270x; 1.1486x over previous
//
#include <hip/hip_runtime.h>

// MarianAttention fused pipeline for MI355X (gfx950).
// B=2, T=2048, D=1024, H=16, DH=64.
//
// Math notes (vs reference):
//  - scores are clamped to [1e-7, 1-1e-7] BEFORE softmax -> exp(S) in [1, e],
//    so no online-max is needed: accumulate l = sum(exp(S)), O = sum(exp(S) V),
//    final O/l. Post-softmax clamp and attn_out clamp are provable no-ops.
//  - exp2-domain: Q is pre-scaled by 0.125*log2(e) (clamp bounds scaled too),
//    so softmax uses raw v_exp_f32 (exp2) with no per-element multiply.
//    Score lower clamp dropped: S >= 0 and |exp(1e-7)-exp(0)| = 1e-7 << tol.
//  - no NaNs can arise from finite inputs -> nan_to_num is a no-op.
//
// R2: attn rewritten around swapped-operand 32x32x16 MFMA (S^T = K*Q^T form):
//     each lane holds one q-row's P values in registers; PV A-fragments are
//     built in-register via v_cvt_pk_bf16 + 2x permlane32_swap per s-slice
//     (T12) -> the sP LDS round-trip is gone. K/V staging double-buffered
//     (T3 minimum 2-phase), one barrier per KV tile.
// R3: fix compile — use exp2f (device fn; v_exp_f32 is base-2 on gfx9).

typedef unsigned short u16;
using bf16x8 = __attribute__((ext_vector_type(8))) __bf16;
using bf16x2 = __attribute__((ext_vector_type(2))) __bf16;
using f32x4  = __attribute__((ext_vector_type(4))) float;
using f32x16 = __attribute__((ext_vector_type(16))) float;
typedef __attribute__((ext_vector_type(2))) int v2i;
typedef __attribute__((ext_vector_type(4))) int v4i;

#define GLD16(g, l) __builtin_amdgcn_global_load_lds(                      \
    (const __attribute__((address_space(1))) void*)(g),                    \
    (__attribute__((address_space(3))) void*)(l), 16, 0, 0)

#define HIL2 1.4426949f   /* (1-1e-7) * log2(e) */

__device__ __forceinline__ float clampf(float x) {
  return fminf(fmaxf(x, 1e-7f), 0.99999988f);
}

__device__ __forceinline__ u16 f2bf(float f) {   // round-half-up f32->bf16 (no NaNs here)
  return (u16)((__float_as_uint(f) + 0x8000u) >> 16);
}

__device__ __forceinline__ int pack2(float a, float b) {  // 2 f32 -> packed bf16x2
  bf16x2 t; t[0] = (__bf16)a; t[1] = (__bf16)b;
  return __builtin_bit_cast(int, t);
}

__device__ __forceinline__ v2i plswap(int a, int b) {     // lane<32 half <-> lane>=32 half
  return __builtin_amdgcn_permlane32_swap(a, b, false, false);
}

// ---------------------------------------------------------------- converts
__global__ __launch_bounds__(256) void cvt_f32_to_bf16(
    const float4* __restrict__ src, ushort4* __restrict__ dst, int n4) {
  int i = blockIdx.x * 256 + threadIdx.x;
  if (i >= n4) return;
  float4 f = src[i];
  ushort4 o;
  o.x = f2bf(f.x); o.y = f2bf(f.y); o.z = f2bf(f.z); o.w = f2bf(f.w);
  dst[i] = o;
}

// ------------------------------------------------------------- GEMM core
// C[M,N] = A[M,1024] * B[N,1024]^T ; 128x128 tile, BK=64, 4 waves (2x2),
// each wave 64x64 = 4x4 frags of 16x16x32 MFMA. m97-style 2-barrier loop.
#define GEMM_CORE(Aptr, Bptr)                                              \
  for (int k0 = 0; k0 < 1024; k0 += 64) {                                  \
    _Pragma("unroll")                                                      \
    for (int i = 0; i < 4; ++i) {                                          \
      const int lin = i * 4096 + tid * 16;                                 \
      const int row = lin >> 7;                                            \
      const int inb = lin & 127;                                           \
      GLD16(Aptr + (size_t)(m0 + row) * 1024 + k0 + (inb >> 1),            \
            (char*)sA + i * 4096 + wave * 1024);                           \
      GLD16(Bptr + (size_t)(n0 + row) * 1024 + k0 + (inb >> 1),            \
            (char*)sB + i * 4096 + wave * 1024);                           \
    }                                                                      \
    __syncthreads();                                                       \
    _Pragma("unroll")                                                      \
    for (int kk = 0; kk < 2; ++kk) {                                       \
      const int ko = kk * 32 + lg * 8;                                     \
      bf16x8 af[4], bfr[4];                                                \
      _Pragma("unroll")                                                    \
      for (int mi = 0; mi < 4; ++mi)                                       \
        af[mi] = *(const bf16x8*)(sA + (wm * 64 + mi * 16 + lr) * 64 + ko);\
      _Pragma("unroll")                                                    \
      for (int ni = 0; ni < 4; ++ni)                                       \
        bfr[ni] = *(const bf16x8*)(sB + (wn * 64 + ni * 16 + lr) * 64 + ko);\
      _Pragma("unroll")                                                    \
      for (int mi = 0; mi < 4; ++mi)                                       \
        _Pragma("unroll")                                                  \
        for (int ni = 0; ni < 4; ++ni)                                     \
          acc[mi][ni] = __builtin_amdgcn_mfma_f32_16x16x32_bf16(           \
              af[mi], bfr[ni], acc[mi][ni], 0, 0, 0);                      \
    }                                                                      \
    __syncthreads();                                                       \
  }

// QKV projection: z=0 -> Q (scale 0.125*log2e), z=1 -> K, z=2 -> V (transposed).
// Q,K out: token-major [4096][1024] bf16. V out: Vt [B*H=32][DH=64][T=2048] bf16.
__global__ __launch_bounds__(256) void gemm_qkv(
    const u16* __restrict__ Xb,
    const u16* __restrict__ Wqb, const u16* __restrict__ Wkb, const u16* __restrict__ Wvb,
    const float* __restrict__ bq, const float* __restrict__ bk, const float* __restrict__ bv,
    u16* __restrict__ Qo, u16* __restrict__ Ko, u16* __restrict__ Vt)
{
  __shared__ u16 sA[128 * 64];
  __shared__ u16 sB[128 * 64];
  const int tid = threadIdx.x, lane = tid & 63, wave = tid >> 6;
  const int lr = lane & 15, lg = lane >> 4;
  const int wm = wave >> 1, wn = wave & 1;
  const int n0 = blockIdx.x * 128, m0 = blockIdx.y * 128;
  const int p = blockIdx.z;
  const u16*   Wb   = (p == 0) ? Wqb : (p == 1) ? Wkb : Wvb;
  const float* bias = (p == 0) ? bq  : (p == 1) ? bk  : bv;

  f32x4 acc[4][4] = {};
  GEMM_CORE(Xb, Wb)

  if (p == 2) {
    // V: write transposed Vt[(b*16+h)*64 + dh][t]; j=0..3 are consecutive t -> pack 8B
    #pragma unroll
    for (int ni = 0; ni < 4; ++ni) {
      const int n = n0 + wn * 64 + ni * 16 + lr;       // feature
      const float bb = bias[n];
      #pragma unroll
      for (int mi = 0; mi < 4; ++mi) {
        const int m = m0 + wm * 64 + mi * 16 + lg * 4; // token (j=0)
        ushort4 pk;
        pk.x = f2bf(clampf(acc[mi][ni][0] + bb));
        pk.y = f2bf(clampf(acc[mi][ni][1] + bb));
        pk.z = f2bf(clampf(acc[mi][ni][2] + bb));
        pk.w = f2bf(clampf(acc[mi][ni][3] + bb));
        *(ushort4*)(Vt + ((size_t)((m >> 11) * 16 + (n >> 6)) * 64 + (n & 63)) * 2048
                       + (m & 2047)) = pk;
      }
    }
  } else {
    u16* O = (p == 0) ? Qo : Ko;
    const float sc  = (p == 0) ? 0.18033688f   : 1.0f;          // 0.125*log2e for Q
    const float clo = (p == 0) ? 1.4426950e-7f : 1e-7f;
    const float chi = (p == 0) ? HIL2          : 0.99999988f;
    #pragma unroll
    for (int ni = 0; ni < 4; ++ni) {
      const int n = n0 + wn * 64 + ni * 16 + lr;
      const float bb = bias[n];
      #pragma unroll
      for (int mi = 0; mi < 4; ++mi) {
        #pragma unroll
        for (int j = 0; j < 4; ++j) {
          const int m = m0 + wm * 64 + mi * 16 + lg * 4 + j;
          O[(size_t)m * 1024 + n] = f2bf(fminf(fmaxf((acc[mi][ni][j] + bb) * sc, clo), chi));
        }
      }
    }
  }
}

// Output projection: out = clamp(AO * Wo^T + bo), fp32 store.
__global__ __launch_bounds__(256) void gemm_out(
    const u16* __restrict__ AOb, const u16* __restrict__ Wob,
    const float* __restrict__ bo, float* __restrict__ out)
{
  __shared__ u16 sA[128 * 64];
  __shared__ u16 sB[128 * 64];
  const int tid = threadIdx.x, lane = tid & 63, wave = tid >> 6;
  const int lr = lane & 15, lg = lane >> 4;
  const int wm = wave >> 1, wn = wave & 1;
  const int n0 = blockIdx.x * 128, m0 = blockIdx.y * 128;

  f32x4 acc[4][4] = {};
  GEMM_CORE(AOb, Wob)

  #pragma unroll
  for (int ni = 0; ni < 4; ++ni) {
    const int n = n0 + wn * 64 + ni * 16 + lr;
    const float bb = bo[n];
    #pragma unroll
    for (int mi = 0; mi < 4; ++mi) {
      #pragma unroll
      for (int j = 0; j < 4; ++j) {
        const int m = m0 + wm * 64 + mi * 16 + lg * 4 + j;
        out[(size_t)m * 1024 + n] = clampf(acc[mi][ni][j] + bb);
      }
    }
  }
}

// ------------------------------------------------------------- attention
// One block per (128 q-rows, b*h). 4 waves; wave w owns q-rows [w*32, w*32+32).
// Swapped QK^T via 32x32x16 MFMA: S^T[s][q] = K * Q^T, so lane (lo=lane&31,
// hi=lane>>5) holds P[q = w*32+lo][s = 32*sf + 4*hi + 8*(reg>>2) + (reg&3)].
// PV A-frag (row=lane&31=q, k=8*hi+j) is built in-register: per 16-wide
// s-slice kk: G0 = regs[8*(kk&1)+0..3], G1 = regs[8*(kk&1)+4..7] of
// sacc[kk>>1]; pack to bf16 pairs; 2x permlane32_swap yields all 4 A-words.
// K/V double-buffered; one __syncthreads per KV tile.
__global__ __launch_bounds__(256) void attn_fused(
    const u16* __restrict__ Qg, const u16* __restrict__ Kg,
    const u16* __restrict__ Vt, u16* __restrict__ AO)
{
  __shared__ u16 sQ[128 * 64];       // [qrow][dh]  sw(r)=(r&7)<<3   (reused as sL after loop)
  __shared__ u16 sK[2][128 * 64];    // [s][dh]     sw(r)=(r&7)<<3
  __shared__ u16 sV[2][64 * 128];    // [dh][s]     sw(r)=(r&15)<<3
  const int tid = threadIdx.x, lane = tid & 63, wave = tid >> 6;
  const int lo = lane & 31, hi = lane >> 5;
  const int qt = blockIdx.x, bh = blockIdx.y;
  const int b = bh >> 4, h = bh & 15;

  auto stageKV = [&](int buf, int s0) {
    #pragma unroll
    for (int i = 0; i < 4; ++i) {
      const int lin = i * 4096 + tid * 16;
      const int row  = lin >> 7;
      const int colk = ((lin & 127) >> 1) ^ ((row & 7) << 3);
      GLD16(Kg + (size_t)(b * 2048 + s0 + row) * 1024 + h * 64 + colk,
            (char*)sK[buf] + i * 4096 + wave * 1024);
      const int rowv = lin >> 8;
      const int colv = ((lin & 255) >> 1) ^ ((rowv & 15) << 3);
      GLD16(Vt + ((size_t)bh * 64 + rowv) * 2048 + s0 + colv,
            (char*)sV[buf] + i * 4096 + wave * 1024);
    }
  };

  // stage Q tile [128][64] (pre-swizzled source) + KV tile 0
  #pragma unroll
  for (int i = 0; i < 4; ++i) {
    const int lin = i * 4096 + tid * 16;
    const int row = lin >> 7;
    const int col = ((lin & 127) >> 1) ^ ((row & 7) << 3);
    GLD16(Qg + (size_t)(b * 2048 + qt * 128 + row) * 1024 + h * 64 + col,
          (char*)sQ + i * 4096 + wave * 1024);
  }
  stageKV(0, 0);
  __syncthreads();

  // hoist this wave's Q fragments (B-operand: col=q=lo, k=8*hi+j, per 16-k step)
  bf16x8 qreg[4];
  #pragma unroll
  for (int ks = 0; ks < 4; ++ks) {
    const int row = wave * 32 + lo;
    qreg[ks] = *(const bf16x8*)(sQ + row * 64 + ((ks * 16 + hi * 8) ^ ((row & 7) << 3)));
  }

  const f32x16 zro = {};
  f32x16 oacc[2] = {};
  float lsum = 0.f;

  for (int t = 0; t < 16; ++t) {
    const int cur = t & 1;
    if (t < 15) stageKV(cur ^ 1, (t + 1) * 128);   // T3: issue next-tile loads first
    const u16* K_ = sK[cur];
    const u16* V_ = sV[cur];

    // S^T = K * Q^T : A = K rows (s), B = Q rows (q). 4 s-frags x 4 k-steps.
    f32x16 sacc[4];
    __builtin_amdgcn_s_setprio(1);
    #pragma unroll
    for (int sf = 0; sf < 4; ++sf) {
      const int row = sf * 32 + lo;
      bf16x8 kf = *(const bf16x8*)(K_ + row * 64 + ((hi * 8) ^ ((lo & 7) << 3)));
      sacc[sf] = __builtin_amdgcn_mfma_f32_32x32x16_bf16(kf, qreg[0], zro, 0, 0, 0);
    }
    #pragma unroll
    for (int ks = 1; ks < 4; ++ks)
      #pragma unroll
      for (int sf = 0; sf < 4; ++sf) {
        const int row = sf * 32 + lo;
        bf16x8 kf = *(const bf16x8*)(K_ + row * 64 + ((ks * 16 + hi * 8) ^ ((lo & 7) << 3)));
        sacc[sf] = __builtin_amdgcn_mfma_f32_32x32x16_bf16(kf, qreg[ks], sacc[sf], 0, 0, 0);
      }

    // fused softmax (exp2-domain) + PV, one 16-wide s-slice at a time
    #pragma unroll
    for (int kk = 0; kk < 8; ++kk) {
      const int sf = kk >> 1, base = (kk & 1) * 8;
      float e[8];
      #pragma unroll
      for (int r = 0; r < 8; ++r) {
        e[r] = exp2f(fminf(sacc[sf][base + r], HIL2));
        lsum += e[r];
      }
      const int pa0 = pack2(e[0], e[1]), pa1 = pack2(e[2], e[3]);
      const int pb0 = pack2(e[4], e[5]), pb1 = pack2(e[6], e[7]);
      const v2i r0 = plswap(pa0, pb0);
      const v2i r1 = plswap(pa1, pb1);
      const v4i wv = {r0[0], r1[0], r0[1], r1[1]};
      const bf16x8 af = __builtin_bit_cast(bf16x8, wv);
      #pragma unroll
      for (int df = 0; df < 2; ++df) {
        const int vr = df * 32 + lo;
        bf16x8 vf = *(const bf16x8*)(V_ + vr * 128 + ((kk * 16 + hi * 8) ^ ((lo & 15) << 3)));
        oacc[df] = __builtin_amdgcn_mfma_f32_32x32x16_bf16(af, vf, oacc[df], 0, 0, 0);
      }
    }
    __builtin_amdgcn_s_setprio(0);
    __syncthreads();
  }

  // row-sum broadcast (q lives at lane lo; O rows live at reg-mapped q)
  const float lfull = lsum + __shfl_xor(lsum, 32);
  float* sL = (float*)sQ;                 // sQ no longer needed; same-wave rw only
  sL[wave * 32 + lo] = lfull;
  #pragma unroll
  for (int g = 0; g < 4; ++g) {
    const float4 l4 = *(const float4*)(sL + wave * 32 + hi * 4 + g * 8);
    #pragma unroll
    for (int r = 0; r < 4; ++r) {
      const float iv = 1.0f / ((const float*)&l4)[r];
      const int m = qt * 128 + wave * 32 + hi * 4 + g * 8 + r;
      #pragma unroll
      for (int df = 0; df < 2; ++df) {
        const float v = oacc[df][g * 4 + r] * iv;
        AO[(size_t)(b * 2048 + m) * 1024 + h * 64 + df * 32 + lo] = f2bf(clampf(v));
      }
    }
  }
}

// ---------------------------------------------------------------- launch
extern "C" void kernel_launch(void* const* d_in, const int* in_sizes, int n_in,
                              void* d_out, int out_size, void* d_ws, size_t ws_size,
                              hipStream_t stream) {
  const float* X  = (const float*)d_in[0];
  const float* Wq = (const float*)d_in[1];
  const float* bq = (const float*)d_in[2];
  const float* Wk = (const float*)d_in[3];
  const float* bk = (const float*)d_in[4];
  const float* Wv = (const float*)d_in[5];
  const float* bv = (const float*)d_in[6];
  const float* Wo = (const float*)d_in[7];
  const float* bo = (const float*)d_in[8];
  float* out = (float*)d_out;

  if (ws_size < (size_t)48 * 1024 * 1024) return;  // fail loudly (output stays poisoned)

  u16* ws  = (u16*)d_ws;
  u16* Xb  = ws;                         // [4096][1024]  8 MB
  u16* Wqb = ws + (size_t)4  * 1048576;  // [1024][1024]  2 MB
  u16* Wkb = ws + (size_t)5  * 1048576;
  u16* Wvb = ws + (size_t)6  * 1048576;
  u16* Wob = ws + (size_t)7  * 1048576;
  u16* Qb  = ws + (size_t)8  * 1048576;  // [4096][1024]  8 MB
  u16* Kb  = ws + (size_t)12 * 1048576;
  u16* Vtb = ws + (size_t)16 * 1048576;  // [32][64][2048] 8 MB
  u16* AOb = ws + (size_t)20 * 1048576;  // [4096][1024]  8 MB

  cvt_f32_to_bf16<<<4096, 256, 0, stream>>>((const float4*)X,  (ushort4*)Xb,  1048576);
  cvt_f32_to_bf16<<<1024, 256, 0, stream>>>((const float4*)Wq, (ushort4*)Wqb, 262144);
  cvt_f32_to_bf16<<<1024, 256, 0, stream>>>((const float4*)Wk, (ushort4*)Wkb, 262144);
  cvt_f32_to_bf16<<<1024, 256, 0, stream>>>((const float4*)Wv, (ushort4*)Wvb, 262144);
  cvt_f32_to_bf16<<<1024, 256, 0, stream>>>((const float4*)Wo, (ushort4*)Wob, 262144);

  gemm_qkv<<<dim3(8, 32, 3), 256, 0, stream>>>(Xb, Wqb, Wkb, Wvb, bq, bk, bv, Qb, Kb, Vtb);
  attn_fused<<<dim3(16, 32), 256, 0, stream>>>(Qb, Kb, Vtb, AOb);
  gemm_out<<<dim3(8, 32), 256, 0, stream>>>(AOb, Wob, bo, out);
}

// Round 5
// 142.103 us; speedup vs baseline: 1.4290x; 1.1647x over previous
//
#include <hip/hip_runtime.h>

// MarianAttention fused pipeline for MI355X (gfx950).
// B=2, T=2048, D=1024, H=16, DH=64.
//
// Math notes (vs reference):
//  - scores are clamped to [1e-7, 1-1e-7] BEFORE softmax -> exp(S) in [1, e],
//    so no online-max is needed: accumulate l = sum(exp(S)), O = sum(exp(S) V),
//    final O/l. Post-softmax clamp and attn_out clamp are provable no-ops.
//  - exp2-domain: Q is pre-scaled by 0.125*log2(e) (clamp bounds scaled too),
//    so softmax uses raw v_exp_f32 (exp2) with no per-element multiply.
//    Score lower clamp dropped: S >= 0 and |exp(1e-7)-exp(0)| = 1e-7 << tol.
//  - no NaNs can arise from finite inputs -> nan_to_num is a no-op.
//
// R2: swapped-operand 32x32x16 MFMA attn (S^T = K*Q^T), P in registers,
//     PV A-frags via cvt_pk + permlane32_swap (T12), K/V double-buffered.
// R4: __launch_bounds__ min-waves hints. R4's VGPR=92 + VALUBusy 64% was the
//     allocator targeting ~5 waves/SIMD and AGPR-spilling the accumulators
//     (LDS caps at 2 blocks/CU anyway). (256,2) -> 256-VGPR budget, no spill.
//     GEMMs get (256,3) (3 blocks/CU grid). lsum: serial chain -> tree-sum.

typedef unsigned short u16;
using bf16x8 = __attribute__((ext_vector_type(8))) __bf16;
using bf16x2 = __attribute__((ext_vector_type(2))) __bf16;
using f32x4  = __attribute__((ext_vector_type(4))) float;
using f32x16 = __attribute__((ext_vector_type(16))) float;
typedef __attribute__((ext_vector_type(2))) int v2i;
typedef __attribute__((ext_vector_type(4))) int v4i;

#define GLD16(g, l) __builtin_amdgcn_global_load_lds(                      \
    (const __attribute__((address_space(1))) void*)(g),                    \
    (__attribute__((address_space(3))) void*)(l), 16, 0, 0)

#define HIL2 1.4426949f   /* (1-1e-7) * log2(e) */

__device__ __forceinline__ float clampf(float x) {
  return fminf(fmaxf(x, 1e-7f), 0.99999988f);
}

__device__ __forceinline__ u16 f2bf(float f) {   // round-half-up f32->bf16 (no NaNs here)
  return (u16)((__float_as_uint(f) + 0x8000u) >> 16);
}

__device__ __forceinline__ int pack2(float a, float b) {  // 2 f32 -> packed bf16x2
  bf16x2 t; t[0] = (__bf16)a; t[1] = (__bf16)b;
  return __builtin_bit_cast(int, t);
}

__device__ __forceinline__ v2i plswap(int a, int b) {     // lane<32 half <-> lane>=32 half
  return __builtin_amdgcn_permlane32_swap(a, b, false, false);
}

// ---------------------------------------------------------------- converts
__global__ __launch_bounds__(256) void cvt_f32_to_bf16(
    const float4* __restrict__ src, ushort4* __restrict__ dst, int n4) {
  int i = blockIdx.x * 256 + threadIdx.x;
  if (i >= n4) return;
  float4 f = src[i];
  ushort4 o;
  o.x = f2bf(f.x); o.y = f2bf(f.y); o.z = f2bf(f.z); o.w = f2bf(f.w);
  dst[i] = o;
}

// ------------------------------------------------------------- GEMM core
// C[M,N] = A[M,1024] * B[N,1024]^T ; 128x128 tile, BK=64, 4 waves (2x2),
// each wave 64x64 = 4x4 frags of 16x16x32 MFMA. m97-style 2-barrier loop.
#define GEMM_CORE(Aptr, Bptr)                                              \
  for (int k0 = 0; k0 < 1024; k0 += 64) {                                  \
    _Pragma("unroll")                                                      \
    for (int i = 0; i < 4; ++i) {                                          \
      const int lin = i * 4096 + tid * 16;                                 \
      const int row = lin >> 7;                                            \
      const int inb = lin & 127;                                           \
      GLD16(Aptr + (size_t)(m0 + row) * 1024 + k0 + (inb >> 1),            \
            (char*)sA + i * 4096 + wave * 1024);                           \
      GLD16(Bptr + (size_t)(n0 + row) * 1024 + k0 + (inb >> 1),            \
            (char*)sB + i * 4096 + wave * 1024);                           \
    }                                                                      \
    __syncthreads();                                                       \
    _Pragma("unroll")                                                      \
    for (int kk = 0; kk < 2; ++kk) {                                       \
      const int ko = kk * 32 + lg * 8;                                     \
      bf16x8 af[4], bfr[4];                                                \
      _Pragma("unroll")                                                    \
      for (int mi = 0; mi < 4; ++mi)                                       \
        af[mi] = *(const bf16x8*)(sA + (wm * 64 + mi * 16 + lr) * 64 + ko);\
      _Pragma("unroll")                                                    \
      for (int ni = 0; ni < 4; ++ni)                                       \
        bfr[ni] = *(const bf16x8*)(sB + (wn * 64 + ni * 16 + lr) * 64 + ko);\
      _Pragma("unroll")                                                    \
      for (int mi = 0; mi < 4; ++mi)                                       \
        _Pragma("unroll")                                                  \
        for (int ni = 0; ni < 4; ++ni)                                     \
          acc[mi][ni] = __builtin_amdgcn_mfma_f32_16x16x32_bf16(           \
              af[mi], bfr[ni], acc[mi][ni], 0, 0, 0);                      \
    }                                                                      \
    __syncthreads();                                                       \
  }

// QKV projection: z=0 -> Q (scale 0.125*log2e), z=1 -> K, z=2 -> V (transposed).
// Q,K out: token-major [4096][1024] bf16. V out: Vt [B*H=32][DH=64][T=2048] bf16.
__global__ __launch_bounds__(256, 3) void gemm_qkv(
    const u16* __restrict__ Xb,
    const u16* __restrict__ Wqb, const u16* __restrict__ Wkb, const u16* __restrict__ Wvb,
    const float* __restrict__ bq, const float* __restrict__ bk, const float* __restrict__ bv,
    u16* __restrict__ Qo, u16* __restrict__ Ko, u16* __restrict__ Vt)
{
  __shared__ u16 sA[128 * 64];
  __shared__ u16 sB[128 * 64];
  const int tid = threadIdx.x, lane = tid & 63, wave = tid >> 6;
  const int lr = lane & 15, lg = lane >> 4;
  const int wm = wave >> 1, wn = wave & 1;
  const int n0 = blockIdx.x * 128, m0 = blockIdx.y * 128;
  const int p = blockIdx.z;
  const u16*   Wb   = (p == 0) ? Wqb : (p == 1) ? Wkb : Wvb;
  const float* bias = (p == 0) ? bq  : (p == 1) ? bk  : bv;

  f32x4 acc[4][4] = {};
  GEMM_CORE(Xb, Wb)

  if (p == 2) {
    // V: write transposed Vt[(b*16+h)*64 + dh][t]; j=0..3 are consecutive t -> pack 8B
    #pragma unroll
    for (int ni = 0; ni < 4; ++ni) {
      const int n = n0 + wn * 64 + ni * 16 + lr;       // feature
      const float bb = bias[n];
      #pragma unroll
      for (int mi = 0; mi < 4; ++mi) {
        const int m = m0 + wm * 64 + mi * 16 + lg * 4; // token (j=0)
        ushort4 pk;
        pk.x = f2bf(clampf(acc[mi][ni][0] + bb));
        pk.y = f2bf(clampf(acc[mi][ni][1] + bb));
        pk.z = f2bf(clampf(acc[mi][ni][2] + bb));
        pk.w = f2bf(clampf(acc[mi][ni][3] + bb));
        *(ushort4*)(Vt + ((size_t)((m >> 11) * 16 + (n >> 6)) * 64 + (n & 63)) * 2048
                       + (m & 2047)) = pk;
      }
    }
  } else {
    u16* O = (p == 0) ? Qo : Ko;
    const float sc  = (p == 0) ? 0.18033688f   : 1.0f;          // 0.125*log2e for Q
    const float clo = (p == 0) ? 1.4426950e-7f : 1e-7f;
    const float chi = (p == 0) ? HIL2          : 0.99999988f;
    #pragma unroll
    for (int ni = 0; ni < 4; ++ni) {
      const int n = n0 + wn * 64 + ni * 16 + lr;
      const float bb = bias[n];
      #pragma unroll
      for (int mi = 0; mi < 4; ++mi) {
        #pragma unroll
        for (int j = 0; j < 4; ++j) {
          const int m = m0 + wm * 64 + mi * 16 + lg * 4 + j;
          O[(size_t)m * 1024 + n] = f2bf(fminf(fmaxf((acc[mi][ni][j] + bb) * sc, clo), chi));
        }
      }
    }
  }
}

// Output projection: out = clamp(AO * Wo^T + bo), fp32 store.
__global__ __launch_bounds__(256, 3) void gemm_out(
    const u16* __restrict__ AOb, const u16* __restrict__ Wob,
    const float* __restrict__ bo, float* __restrict__ out)
{
  __shared__ u16 sA[128 * 64];
  __shared__ u16 sB[128 * 64];
  const int tid = threadIdx.x, lane = tid & 63, wave = tid >> 6;
  const int lr = lane & 15, lg = lane >> 4;
  const int wm = wave >> 1, wn = wave & 1;
  const int n0 = blockIdx.x * 128, m0 = blockIdx.y * 128;

  f32x4 acc[4][4] = {};
  GEMM_CORE(AOb, Wob)

  #pragma unroll
  for (int ni = 0; ni < 4; ++ni) {
    const int n = n0 + wn * 64 + ni * 16 + lr;
    const float bb = bo[n];
    #pragma unroll
    for (int mi = 0; mi < 4; ++mi) {
      #pragma unroll
      for (int j = 0; j < 4; ++j) {
        const int m = m0 + wm * 64 + mi * 16 + lg * 4 + j;
        out[(size_t)m * 1024 + n] = clampf(acc[mi][ni][j] + bb);
      }
    }
  }
}

// ------------------------------------------------------------- attention
// One block per (128 q-rows, b*h). 4 waves; wave w owns q-rows [w*32, w*32+32).
// Swapped QK^T via 32x32x16 MFMA: S^T[s][q] = K * Q^T, so lane (lo=lane&31,
// hi=lane>>5) holds P[q = w*32+lo][s = 32*sf + 4*hi + 8*(reg>>2) + (reg&3)].
// PV A-frag (row=lane&31=q, k=8*hi+j) is built in-register via cvt_pk +
// 2x permlane32_swap per 16-wide s-slice. K/V double-buffered; one
// __syncthreads per KV tile. (256,2): LDS caps at 2 blocks/CU, so give the
// allocator the full 256-VGPR budget -> no accumulator spills.
__global__ __launch_bounds__(256, 2) void attn_fused(
    const u16* __restrict__ Qg, const u16* __restrict__ Kg,
    const u16* __restrict__ Vt, u16* __restrict__ AO)
{
  __shared__ u16 sQ[128 * 64];       // [qrow][dh]  sw(r)=(r&7)<<3   (reused as sL after loop)
  __shared__ u16 sK[2][128 * 64];    // [s][dh]     sw(r)=(r&7)<<3
  __shared__ u16 sV[2][64 * 128];    // [dh][s]     sw(r)=(r&15)<<3
  const int tid = threadIdx.x, lane = tid & 63, wave = tid >> 6;
  const int lo = lane & 31, hi = lane >> 5;
  const int qt = blockIdx.x, bh = blockIdx.y;
  const int b = bh >> 4, h = bh & 15;

  auto stageKV = [&](int buf, int s0) {
    #pragma unroll
    for (int i = 0; i < 4; ++i) {
      const int lin = i * 4096 + tid * 16;
      const int row  = lin >> 7;
      const int colk = ((lin & 127) >> 1) ^ ((row & 7) << 3);
      GLD16(Kg + (size_t)(b * 2048 + s0 + row) * 1024 + h * 64 + colk,
            (char*)sK[buf] + i * 4096 + wave * 1024);
      const int rowv = lin >> 8;
      const int colv = ((lin & 255) >> 1) ^ ((rowv & 15) << 3);
      GLD16(Vt + ((size_t)bh * 64 + rowv) * 2048 + s0 + colv,
            (char*)sV[buf] + i * 4096 + wave * 1024);
    }
  };

  // stage Q tile [128][64] (pre-swizzled source) + KV tile 0
  #pragma unroll
  for (int i = 0; i < 4; ++i) {
    const int lin = i * 4096 + tid * 16;
    const int row = lin >> 7;
    const int col = ((lin & 127) >> 1) ^ ((row & 7) << 3);
    GLD16(Qg + (size_t)(b * 2048 + qt * 128 + row) * 1024 + h * 64 + col,
          (char*)sQ + i * 4096 + wave * 1024);
  }
  stageKV(0, 0);
  __syncthreads();

  // hoist this wave's Q fragments (B-operand: col=q=lo, k=8*hi+j, per 16-k step)
  bf16x8 qreg[4];
  #pragma unroll
  for (int ks = 0; ks < 4; ++ks) {
    const int row = wave * 32 + lo;
    qreg[ks] = *(const bf16x8*)(sQ + row * 64 + ((ks * 16 + hi * 8) ^ ((row & 7) << 3)));
  }

  const f32x16 zro = {};
  f32x16 oacc[2] = {};
  float lsum = 0.f;

  for (int t = 0; t < 16; ++t) {
    const int cur = t & 1;
    if (t < 15) stageKV(cur ^ 1, (t + 1) * 128);   // T3: issue next-tile loads first
    const u16* K_ = sK[cur];
    const u16* V_ = sV[cur];

    // S^T = K * Q^T : A = K rows (s), B = Q rows (q). 4 s-frags x 4 k-steps.
    f32x16 sacc[4];
    __builtin_amdgcn_s_setprio(1);
    #pragma unroll
    for (int sf = 0; sf < 4; ++sf) {
      const int row = sf * 32 + lo;
      bf16x8 kf = *(const bf16x8*)(K_ + row * 64 + ((hi * 8) ^ ((lo & 7) << 3)));
      sacc[sf] = __builtin_amdgcn_mfma_f32_32x32x16_bf16(kf, qreg[0], zro, 0, 0, 0);
    }
    #pragma unroll
    for (int ks = 1; ks < 4; ++ks)
      #pragma unroll
      for (int sf = 0; sf < 4; ++sf) {
        const int row = sf * 32 + lo;
        bf16x8 kf = *(const bf16x8*)(K_ + row * 64 + ((ks * 16 + hi * 8) ^ ((lo & 7) << 3)));
        sacc[sf] = __builtin_amdgcn_mfma_f32_32x32x16_bf16(kf, qreg[ks], sacc[sf], 0, 0, 0);
      }

    // fused softmax (exp2-domain) + PV, one 16-wide s-slice at a time
    #pragma unroll
    for (int kk = 0; kk < 8; ++kk) {
      const int sf = kk >> 1, base = (kk & 1) * 8;
      float e[8];
      #pragma unroll
      for (int r = 0; r < 8; ++r)
        e[r] = exp2f(fminf(sacc[sf][base + r], HIL2));
      // tree-sum (breaks the serial dependent-add chain)
      lsum += ((e[0] + e[1]) + (e[2] + e[3])) + ((e[4] + e[5]) + (e[6] + e[7]));
      const int pa0 = pack2(e[0], e[1]), pa1 = pack2(e[2], e[3]);
      const int pb0 = pack2(e[4], e[5]), pb1 = pack2(e[6], e[7]);
      const v2i r0 = plswap(pa0, pb0);
      const v2i r1 = plswap(pa1, pb1);
      const v4i wv = {r0[0], r1[0], r0[1], r1[1]};
      const bf16x8 af = __builtin_bit_cast(bf16x8, wv);
      #pragma unroll
      for (int df = 0; df < 2; ++df) {
        const int vr = df * 32 + lo;
        bf16x8 vf = *(const bf16x8*)(V_ + vr * 128 + ((kk * 16 + hi * 8) ^ ((lo & 15) << 3)));
        oacc[df] = __builtin_amdgcn_mfma_f32_32x32x16_bf16(af, vf, oacc[df], 0, 0, 0);
      }
    }
    __builtin_amdgcn_s_setprio(0);
    __syncthreads();
  }

  // row-sum broadcast (q lives at lane lo; O rows live at reg-mapped q)
  const float lfull = lsum + __shfl_xor(lsum, 32);
  float* sL = (float*)sQ;                 // sQ no longer needed; same-wave rw only
  sL[wave * 32 + lo] = lfull;
  #pragma unroll
  for (int g = 0; g < 4; ++g) {
    const float4 l4 = *(const float4*)(sL + wave * 32 + hi * 4 + g * 8);
    #pragma unroll
    for (int r = 0; r < 4; ++r) {
      const float iv = 1.0f / ((const float*)&l4)[r];
      const int m = qt * 128 + wave * 32 + hi * 4 + g * 8 + r;
      #pragma unroll
      for (int df = 0; df < 2; ++df) {
        const float v = oacc[df][g * 4 + r] * iv;
        AO[(size_t)(b * 2048 + m) * 1024 + h * 64 + df * 32 + lo] = f2bf(clampf(v));
      }
    }
  }
}

// ---------------------------------------------------------------- launch
extern "C" void kernel_launch(void* const* d_in, const int* in_sizes, int n_in,
                              void* d_out, int out_size, void* d_ws, size_t ws_size,
                              hipStream_t stream) {
  const float* X  = (const float*)d_in[0];
  const float* Wq = (const float*)d_in[1];
  const float* bq = (const float*)d_in[2];
  const float* Wk = (const float*)d_in[3];
  const float* bk = (const float*)d_in[4];
  const float* Wv = (const float*)d_in[5];
  const float* bv = (const float*)d_in[6];
  const float* Wo = (const float*)d_in[7];
  const float* bo = (const float*)d_in[8];
  float* out = (float*)d_out;

  if (ws_size < (size_t)48 * 1024 * 1024) return;  // fail loudly (output stays poisoned)

  u16* ws  = (u16*)d_ws;
  u16* Xb  = ws;                         // [4096][1024]  8 MB
  u16* Wqb = ws + (size_t)4  * 1048576;  // [1024][1024]  2 MB
  u16* Wkb = ws + (size_t)5  * 1048576;
  u16* Wvb = ws + (size_t)6  * 1048576;
  u16* Wob = ws + (size_t)7  * 1048576;
  u16* Qb  = ws + (size_t)8  * 1048576;  // [4096][1024]  8 MB
  u16* Kb  = ws + (size_t)12 * 1048576;
  u16* Vtb = ws + (size_t)16 * 1048576;  // [32][64][2048] 8 MB
  u16* AOb = ws + (size_t)20 * 1048576;  // [4096][1024]  8 MB

  cvt_f32_to_bf16<<<4096, 256, 0, stream>>>((const float4*)X,  (ushort4*)Xb,  1048576);
  cvt_f32_to_bf16<<<1024, 256, 0, stream>>>((const float4*)Wq, (ushort4*)Wqb, 262144);
  cvt_f32_to_bf16<<<1024, 256, 0, stream>>>((const float4*)Wk, (ushort4*)Wkb, 262144);
  cvt_f32_to_bf16<<<1024, 256, 0, stream>>>((const float4*)Wv, (ushort4*)Wvb, 262144);
  cvt_f32_to_bf16<<<1024, 256, 0, stream>>>((const float4*)Wo, (ushort4*)Wob, 262144);

  gemm_qkv<<<dim3(8, 32, 3), 256, 0, stream>>>(Xb, Wqb, Wkb, Wvb, bq, bk, bv, Qb, Kb, Vtb);
  attn_fused<<<dim3(16, 32), 256, 0, stream>>>(Qb, Kb, Vtb, AOb);
  gemm_out<<<dim3(8, 32), 256, 0, stream>>>(AOb, Wob, bo, out);
}

// Round 6
// 117.866 us; speedup vs baseline: 1.7229x; 1.2056x over previous
//
#include <hip/hip_runtime.h>

// MarianAttention fused pipeline for MI355X (gfx950).
// B=2, T=2048, D=1024, H=16, DH=64.
//
// Math notes (vs reference):
//  - scores are clamped to [1e-7, 1-1e-7] BEFORE softmax -> exp(S) in [1, e],
//    so no online-max is needed: accumulate l = sum(exp(S)), O = sum(exp(S) V),
//    final O/l. Post-softmax clamp and attn_out clamp are provable no-ops.
//  - exp2-domain: Q is pre-scaled by 0.125*log2(e), so softmax is a single
//    v_exp_f32 per element (__builtin_amdgcn_exp2f; domain [0,1.443] is safe).
//  - no NaNs can arise from finite inputs -> nan_to_num is a no-op.
//
// R2: swapped-operand 32x32x16 MFMA attn (S^T = K*Q^T), P in registers,
//     PV A-frags via cvt_pk + permlane32_swap (T12), K/V double-buffered.
// R4: launch_bounds (256,2)/(256,3); tree-sum lsum.
// R6: VALU-count attack. R5 showed attn VALUBusy 60% = real instructions:
//     OCML exp2f expansion, per-tile recompute of 32 swizzled LDS addresses,
//     per-tile global-address recompute. Fixes: __builtin_amdgcn_exp2f;
//     koff/voff hoisted to registers + tile loop unrolled x2 so the LDS
//     buffer base folds into ds_read offset immediates; loop-carried global
//     staging pointers. Weight converts fused into one launch.

typedef unsigned short u16;
using bf16x8 = __attribute__((ext_vector_type(8))) __bf16;
using bf16x2 = __attribute__((ext_vector_type(2))) __bf16;
using f32x4  = __attribute__((ext_vector_type(4))) float;
using f32x16 = __attribute__((ext_vector_type(16))) float;
typedef __attribute__((ext_vector_type(2))) int v2i;
typedef __attribute__((ext_vector_type(4))) int v4i;

#define GLD16(g, l) __builtin_amdgcn_global_load_lds(                      \
    (const __attribute__((address_space(1))) void*)(g),                    \
    (__attribute__((address_space(3))) void*)(l), 16, 0, 0)

#define HIL2 1.4426949f   /* (1-1e-7) * log2(e) */

__device__ __forceinline__ float clampf(float x) {
  return fminf(fmaxf(x, 1e-7f), 0.99999988f);
}

__device__ __forceinline__ u16 f2bf(float f) {   // round-half-up f32->bf16 (no NaNs here)
  return (u16)((__float_as_uint(f) + 0x8000u) >> 16);
}

__device__ __forceinline__ int pack2(float a, float b) {  // 2 f32 -> packed bf16x2
  bf16x2 t; t[0] = (__bf16)a; t[1] = (__bf16)b;
  return __builtin_bit_cast(int, t);
}

__device__ __forceinline__ v2i plswap(int a, int b) {     // lane<32 half <-> lane>=32 half
  return __builtin_amdgcn_permlane32_swap(a, b, false, false);
}

// ---------------------------------------------------------------- converts
__global__ __launch_bounds__(256) void cvt_f32_to_bf16(
    const float4* __restrict__ src, ushort4* __restrict__ dst, int n4) {
  int i = blockIdx.x * 256 + threadIdx.x;
  if (i >= n4) return;
  float4 f = src[i];
  ushort4 o;
  o.x = f2bf(f.x); o.y = f2bf(f.y); o.z = f2bf(f.z); o.w = f2bf(f.w);
  dst[i] = o;
}

// all four 1024x1024 weights in one launch (blockIdx.y selects)
__global__ __launch_bounds__(256) void cvt_w4(
    const float4* __restrict__ w0, const float4* __restrict__ w1,
    const float4* __restrict__ w2, const float4* __restrict__ w3,
    ushort4* __restrict__ o0, ushort4* __restrict__ o1,
    ushort4* __restrict__ o2, ushort4* __restrict__ o3) {
  const int p = blockIdx.y;
  const float4* src = (p == 0) ? w0 : (p == 1) ? w1 : (p == 2) ? w2 : w3;
  ushort4*      dst = (p == 0) ? o0 : (p == 1) ? o1 : (p == 2) ? o2 : o3;
  int i = blockIdx.x * 256 + threadIdx.x;
  float4 f = src[i];
  ushort4 o;
  o.x = f2bf(f.x); o.y = f2bf(f.y); o.z = f2bf(f.z); o.w = f2bf(f.w);
  dst[i] = o;
}

// ------------------------------------------------------------- GEMM core
// C[M,N] = A[M,1024] * B[N,1024]^T ; 128x128 tile, BK=64, 4 waves (2x2),
// each wave 64x64 = 4x4 frags of 16x16x32 MFMA. m97-style 2-barrier loop.
#define GEMM_CORE(Aptr, Bptr)                                              \
  for (int k0 = 0; k0 < 1024; k0 += 64) {                                  \
    _Pragma("unroll")                                                      \
    for (int i = 0; i < 4; ++i) {                                          \
      const int lin = i * 4096 + tid * 16;                                 \
      const int row = lin >> 7;                                            \
      const int inb = lin & 127;                                           \
      GLD16(Aptr + (size_t)(m0 + row) * 1024 + k0 + (inb >> 1),            \
            (char*)sA + i * 4096 + wave * 1024);                           \
      GLD16(Bptr + (size_t)(n0 + row) * 1024 + k0 + (inb >> 1),            \
            (char*)sB + i * 4096 + wave * 1024);                           \
    }                                                                      \
    __syncthreads();                                                       \
    _Pragma("unroll")                                                      \
    for (int kk = 0; kk < 2; ++kk) {                                       \
      const int ko = kk * 32 + lg * 8;                                     \
      bf16x8 af[4], bfr[4];                                                \
      _Pragma("unroll")                                                    \
      for (int mi = 0; mi < 4; ++mi)                                       \
        af[mi] = *(const bf16x8*)(sA + (wm * 64 + mi * 16 + lr) * 64 + ko);\
      _Pragma("unroll")                                                    \
      for (int ni = 0; ni < 4; ++ni)                                       \
        bfr[ni] = *(const bf16x8*)(sB + (wn * 64 + ni * 16 + lr) * 64 + ko);\
      _Pragma("unroll")                                                    \
      for (int mi = 0; mi < 4; ++mi)                                       \
        _Pragma("unroll")                                                  \
        for (int ni = 0; ni < 4; ++ni)                                     \
          acc[mi][ni] = __builtin_amdgcn_mfma_f32_16x16x32_bf16(           \
              af[mi], bfr[ni], acc[mi][ni], 0, 0, 0);                      \
    }                                                                      \
    __syncthreads();                                                       \
  }

// QKV projection: z=0 -> Q (scale 0.125*log2e), z=1 -> K, z=2 -> V (transposed).
// Q,K out: token-major [4096][1024] bf16. V out: Vt [B*H=32][DH=64][T=2048] bf16.
__global__ __launch_bounds__(256, 3) void gemm_qkv(
    const u16* __restrict__ Xb,
    const u16* __restrict__ Wqb, const u16* __restrict__ Wkb, const u16* __restrict__ Wvb,
    const float* __restrict__ bq, const float* __restrict__ bk, const float* __restrict__ bv,
    u16* __restrict__ Qo, u16* __restrict__ Ko, u16* __restrict__ Vt)
{
  __shared__ u16 sA[128 * 64];
  __shared__ u16 sB[128 * 64];
  const int tid = threadIdx.x, lane = tid & 63, wave = tid >> 6;
  const int lr = lane & 15, lg = lane >> 4;
  const int wm = wave >> 1, wn = wave & 1;
  const int n0 = blockIdx.x * 128, m0 = blockIdx.y * 128;
  const int p = blockIdx.z;
  const u16*   Wb   = (p == 0) ? Wqb : (p == 1) ? Wkb : Wvb;
  const float* bias = (p == 0) ? bq  : (p == 1) ? bk  : bv;

  f32x4 acc[4][4] = {};
  GEMM_CORE(Xb, Wb)

  if (p == 2) {
    // V: write transposed Vt[(b*16+h)*64 + dh][t]; j=0..3 are consecutive t -> pack 8B
    #pragma unroll
    for (int ni = 0; ni < 4; ++ni) {
      const int n = n0 + wn * 64 + ni * 16 + lr;       // feature
      const float bb = bias[n];
      #pragma unroll
      for (int mi = 0; mi < 4; ++mi) {
        const int m = m0 + wm * 64 + mi * 16 + lg * 4; // token (j=0)
        ushort4 pk;
        pk.x = f2bf(clampf(acc[mi][ni][0] + bb));
        pk.y = f2bf(clampf(acc[mi][ni][1] + bb));
        pk.z = f2bf(clampf(acc[mi][ni][2] + bb));
        pk.w = f2bf(clampf(acc[mi][ni][3] + bb));
        *(ushort4*)(Vt + ((size_t)((m >> 11) * 16 + (n >> 6)) * 64 + (n & 63)) * 2048
                       + (m & 2047)) = pk;
      }
    }
  } else {
    u16* O = (p == 0) ? Qo : Ko;
    const float sc  = (p == 0) ? 0.18033688f   : 1.0f;          // 0.125*log2e for Q
    const float clo = (p == 0) ? 1.4426950e-7f : 1e-7f;
    const float chi = (p == 0) ? HIL2          : 0.99999988f;
    #pragma unroll
    for (int ni = 0; ni < 4; ++ni) {
      const int n = n0 + wn * 64 + ni * 16 + lr;
      const float bb = bias[n];
      #pragma unroll
      for (int mi = 0; mi < 4; ++mi) {
        #pragma unroll
        for (int j = 0; j < 4; ++j) {
          const int m = m0 + wm * 64 + mi * 16 + lg * 4 + j;
          O[(size_t)m * 1024 + n] = f2bf(fminf(fmaxf((acc[mi][ni][j] + bb) * sc, clo), chi));
        }
      }
    }
  }
}

// Output projection: out = clamp(AO * Wo^T + bo), fp32 store.
__global__ __launch_bounds__(256, 3) void gemm_out(
    const u16* __restrict__ AOb, const u16* __restrict__ Wob,
    const float* __restrict__ bo, float* __restrict__ out)
{
  __shared__ u16 sA[128 * 64];
  __shared__ u16 sB[128 * 64];
  const int tid = threadIdx.x, lane = tid & 63, wave = tid >> 6;
  const int lr = lane & 15, lg = lane >> 4;
  const int wm = wave >> 1, wn = wave & 1;
  const int n0 = blockIdx.x * 128, m0 = blockIdx.y * 128;

  f32x4 acc[4][4] = {};
  GEMM_CORE(AOb, Wob)

  #pragma unroll
  for (int ni = 0; ni < 4; ++ni) {
    const int n = n0 + wn * 64 + ni * 16 + lr;
    const float bb = bo[n];
    #pragma unroll
    for (int mi = 0; mi < 4; ++mi) {
      #pragma unroll
      for (int j = 0; j < 4; ++j) {
        const int m = m0 + wm * 64 + mi * 16 + lg * 4 + j;
        out[(size_t)m * 1024 + n] = clampf(acc[mi][ni][j] + bb);
      }
    }
  }
}

// ------------------------------------------------------------- attention
// One block per (128 q-rows, b*h). 4 waves; wave w owns q-rows [w*32, w*32+32).
// Swapped QK^T via 32x32x16 MFMA: S^T[s][q] = K * Q^T, so lane (lo=lane&31,
// hi=lane>>5) holds P[q = w*32+lo][s = 32*sf + 4*hi + 8*(reg>>2) + (reg&3)].
// PV A-frag built in-register via cvt_pk + 2x permlane32_swap per s-slice.
// K/V double-buffered; tile loop unrolled x2 so the LDS buffer is
// compile-time (ds_read offsets fold to immediates); all swizzled LDS
// offsets precomputed once into registers; global staging pointers are
// loop-carried. One __syncthreads per KV tile.
__global__ __launch_bounds__(256, 2) void attn_fused(
    const u16* __restrict__ Qg, const u16* __restrict__ Kg,
    const u16* __restrict__ Vt, u16* __restrict__ AO)
{
  __shared__ u16 sK[2][128 * 64];    // [s][dh]     sw(r)=(r&7)<<3
  __shared__ u16 sV[2][64 * 128];    // [dh][s]     sw(r)=(r&15)<<3
  __shared__ u16 sQ[128 * 64];       // [qrow][dh]  sw(r)=(r&7)<<3  (reused as sL)
  const int tid = threadIdx.x, lane = tid & 63, wave = tid >> 6;
  const int lo = lane & 31, hi = lane >> 5;
  const int qt = blockIdx.x, bh = blockIdx.y;
  const int b = bh >> 4, h = bh & 15;

  // loop-carried global staging pointers (advance by one KV tile per stage)
  const u16* kgp[4];
  const u16* vgp[4];
  #pragma unroll
  for (int i = 0; i < 4; ++i) {
    const int lin = i * 4096 + tid * 16;
    const int row  = lin >> 7;
    const int colk = ((lin & 127) >> 1) ^ ((row & 7) << 3);
    kgp[i] = Kg + (size_t)(b * 2048 + row) * 1024 + h * 64 + colk;
    const int rowv = lin >> 8;
    const int colv = ((lin & 255) >> 1) ^ ((rowv & 15) << 3);
    vgp[i] = Vt + ((size_t)bh * 64 + rowv) * 2048 + colv;
  }

  // precomputed swizzled LDS byte offsets (static-indexed -> stay in VGPRs)
  int koff[4][4];   // [ks][sf]
  #pragma unroll
  for (int ks = 0; ks < 4; ++ks)
    #pragma unroll
    for (int sf = 0; sf < 4; ++sf)
      koff[ks][sf] = ((sf * 32 + lo) * 64 + ((ks * 16 + hi * 8) ^ ((lo & 7) << 3))) * 2;
  int voff[8][2];   // [kk][df]
  #pragma unroll
  for (int kk = 0; kk < 8; ++kk)
    #pragma unroll
    for (int df = 0; df < 2; ++df)
      voff[kk][df] = ((df * 32 + lo) * 128 + ((kk * 16 + hi * 8) ^ ((lo & 15) << 3))) * 2;

  // stage Q tile + KV tile 0 (buf 0)
  #pragma unroll
  for (int i = 0; i < 4; ++i) {
    const int lin = i * 4096 + tid * 16;
    const int row = lin >> 7;
    const int col = ((lin & 127) >> 1) ^ ((row & 7) << 3);
    GLD16(Qg + (size_t)(b * 2048 + qt * 128 + row) * 1024 + h * 64 + col,
          (char*)sQ + i * 4096 + wave * 1024);
    GLD16(kgp[i], (char*)sK[0] + i * 4096 + wave * 1024);
    GLD16(vgp[i], (char*)sV[0] + i * 4096 + wave * 1024);
    kgp[i] += 128 * 1024;
    vgp[i] += 128;
  }
  __syncthreads();

  // hoist this wave's Q fragments (B-operand: col=q=lo, k=8*hi+j, per 16-k step)
  bf16x8 qreg[4];
  #pragma unroll
  for (int ks = 0; ks < 4; ++ks) {
    const int row = wave * 32 + lo;
    qreg[ks] = *(const bf16x8*)(sQ + row * 64 + ((ks * 16 + hi * 8) ^ ((row & 7) << 3)));
  }

  const f32x16 zro = {};
  f32x16 oacc[2] = {};
  float lsum = 0.f;

  for (int tp = 0; tp < 8; ++tp) {
    #pragma unroll
    for (int half = 0; half < 2; ++half) {       // buf = half: compile-time
      const int t = tp * 2 + half;
      if (t < 15) {                              // stage tile t+1 into buf half^1
        #pragma unroll
        for (int i = 0; i < 4; ++i) {
          GLD16(kgp[i], (char*)sK[half ^ 1] + i * 4096 + wave * 1024);
          GLD16(vgp[i], (char*)sV[half ^ 1] + i * 4096 + wave * 1024);
          kgp[i] += 128 * 1024;
          vgp[i] += 128;
        }
      }
      const char* Kb = (const char*)sK[half];
      const char* Vb = (const char*)sV[half];

      // S^T = K * Q^T : A = K rows (s), B = Q rows (q). 4 s-frags x 4 k-steps.
      f32x16 sacc[4];
      __builtin_amdgcn_s_setprio(1);
      #pragma unroll
      for (int sf = 0; sf < 4; ++sf) {
        bf16x8 kf = *(const bf16x8*)(Kb + koff[0][sf]);
        sacc[sf] = __builtin_amdgcn_mfma_f32_32x32x16_bf16(kf, qreg[0], zro, 0, 0, 0);
      }
      #pragma unroll
      for (int ks = 1; ks < 4; ++ks)
        #pragma unroll
        for (int sf = 0; sf < 4; ++sf) {
          bf16x8 kf = *(const bf16x8*)(Kb + koff[ks][sf]);
          sacc[sf] = __builtin_amdgcn_mfma_f32_32x32x16_bf16(kf, qreg[ks], sacc[sf], 0, 0, 0);
        }

      // fused softmax (single v_exp_f32 per elem) + PV, 16-wide s-slices
      #pragma unroll
      for (int kk = 0; kk < 8; ++kk) {
        const int sf = kk >> 1, base = (kk & 1) * 8;
        float e[8];
        #pragma unroll
        for (int r = 0; r < 8; ++r)
          e[r] = __builtin_amdgcn_exp2f(fminf(sacc[sf][base + r], HIL2));
        lsum += ((e[0] + e[1]) + (e[2] + e[3])) + ((e[4] + e[5]) + (e[6] + e[7]));
        const int pa0 = pack2(e[0], e[1]), pa1 = pack2(e[2], e[3]);
        const int pb0 = pack2(e[4], e[5]), pb1 = pack2(e[6], e[7]);
        const v2i r0 = plswap(pa0, pb0);
        const v2i r1 = plswap(pa1, pb1);
        const v4i wv = {r0[0], r1[0], r0[1], r1[1]};
        const bf16x8 af = __builtin_bit_cast(bf16x8, wv);
        #pragma unroll
        for (int df = 0; df < 2; ++df) {
          bf16x8 vf = *(const bf16x8*)(Vb + voff[kk][df]);
          oacc[df] = __builtin_amdgcn_mfma_f32_32x32x16_bf16(af, vf, oacc[df], 0, 0, 0);
        }
      }
      __builtin_amdgcn_s_setprio(0);
      __syncthreads();
    }
  }

  // row-sum broadcast (q lives at lane lo; O rows live at reg-mapped q)
  const float lfull = lsum + __shfl_xor(lsum, 32);
  float* sL = (float*)sQ;                 // sQ no longer needed; same-wave rw only
  sL[wave * 32 + lo] = lfull;
  #pragma unroll
  for (int g = 0; g < 4; ++g) {
    const float4 l4 = *(const float4*)(sL + wave * 32 + hi * 4 + g * 8);
    #pragma unroll
    for (int r = 0; r < 4; ++r) {
      const float iv = 1.0f / ((const float*)&l4)[r];
      const int m = qt * 128 + wave * 32 + hi * 4 + g * 8 + r;
      #pragma unroll
      for (int df = 0; df < 2; ++df) {
        const float v = oacc[df][g * 4 + r] * iv;
        AO[(size_t)(b * 2048 + m) * 1024 + h * 64 + df * 32 + lo] = f2bf(clampf(v));
      }
    }
  }
}

// ---------------------------------------------------------------- launch
extern "C" void kernel_launch(void* const* d_in, const int* in_sizes, int n_in,
                              void* d_out, int out_size, void* d_ws, size_t ws_size,
                              hipStream_t stream) {
  const float* X  = (const float*)d_in[0];
  const float* Wq = (const float*)d_in[1];
  const float* bq = (const float*)d_in[2];
  const float* Wk = (const float*)d_in[3];
  const float* bk = (const float*)d_in[4];
  const float* Wv = (const float*)d_in[5];
  const float* bv = (const float*)d_in[6];
  const float* Wo = (const float*)d_in[7];
  const float* bo = (const float*)d_in[8];
  float* out = (float*)d_out;

  if (ws_size < (size_t)48 * 1024 * 1024) return;  // fail loudly (output stays poisoned)

  u16* ws  = (u16*)d_ws;
  u16* Xb  = ws;                         // [4096][1024]  8 MB
  u16* Wqb = ws + (size_t)4  * 1048576;  // [1024][1024]  2 MB
  u16* Wkb = ws + (size_t)5  * 1048576;
  u16* Wvb = ws + (size_t)6  * 1048576;
  u16* Wob = ws + (size_t)7  * 1048576;
  u16* Qb  = ws + (size_t)8  * 1048576;  // [4096][1024]  8 MB
  u16* Kb  = ws + (size_t)12 * 1048576;
  u16* Vtb = ws + (size_t)16 * 1048576;  // [32][64][2048] 8 MB
  u16* AOb = ws + (size_t)20 * 1048576;  // [4096][1024]  8 MB

  cvt_f32_to_bf16<<<4096, 256, 0, stream>>>((const float4*)X, (ushort4*)Xb, 1048576);
  cvt_w4<<<dim3(1024, 4), 256, 0, stream>>>(
      (const float4*)Wq, (const float4*)Wk, (const float4*)Wv, (const float4*)Wo,
      (ushort4*)Wqb, (ushort4*)Wkb, (ushort4*)Wvb, (ushort4*)Wob);

  gemm_qkv<<<dim3(8, 32, 3), 256, 0, stream>>>(Xb, Wqb, Wkb, Wvb, bq, bk, bv, Qb, Kb, Vtb);
  attn_fused<<<dim3(16, 32), 256, 0, stream>>>(Qb, Kb, Vtb, AOb);
  gemm_out<<<dim3(8, 32), 256, 0, stream>>>(AOb, Wob, bo, out);
}